// Round 10
// baseline (254.851 us; speedup 1.0000x reference)
//
#include <hip/hip_runtime.h>
#include <hip/hip_bf16.h>
#include <math.h>

#define D 128
#define EPS 1e-12f
#define CPAD 16   // one counter per 64B cache line: kills same-line atomic serialization

typedef __attribute__((ext_vector_type(8))) short bf16x8;
typedef __attribute__((ext_vector_type(4))) float f32x4;
typedef __attribute__((ext_vector_type(2))) float f32x2;

// float -> bf16 round-to-nearest-even (finite inputs)
__device__ __forceinline__ unsigned short f2bf(float f) {
    unsigned int u = __float_as_uint(f);
    return (unsigned short)((u + 0x7fffu + ((u >> 16) & 1u)) >> 16);
}
__device__ __forceinline__ float bf2f_lo(unsigned int packed) {
    return __uint_as_float(packed << 16);
}
__device__ __forceinline__ float bf2f_hi(unsigned int packed) {
    return __uint_as_float(packed & 0xffff0000u);
}
__device__ __forceinline__ unsigned char f2fp8(float f) {
    return (unsigned char)__builtin_amdgcn_cvt_pk_fp8_f32(f, f, 0, false);
}

// ---------------- merged: W convert to MFMA-fragment order (blocks 0..63) + degree count ----------------
// Fragment order: WT[m*16384 + ((ct*4+ks)*64 + quad*16 + l15)*8 + j]
//   holds element (n = ct*16+l15, k = ks*32+quad*8+j) of W_m^T  (bf16)
// Edge blocks only count degrees now (no ticket store — scatter claims slots itself).
__global__ __launch_bounds__(256) void prep_kernel(
    const float* __restrict__ Wq, const float* __restrict__ Wk,
    const float* __restrict__ Wv, const float* __restrict__ Wo,
    unsigned short* __restrict__ WT,
    const int* __restrict__ dst, int* __restrict__ counts, int E) {
    int bx = blockIdx.x;
    int tid = threadIdx.x;
    if (bx < 64) {
        __shared__ unsigned short tile[32][33];
        int m = bx >> 4;
        int t = bx & 15;
        const float* W = (m == 0) ? Wq : (m == 1) ? Wk : (m == 2) ? Wv : Wo;
        int r0 = (t & 3) * 32;   // k block
        int c0 = (t >> 2) * 32;  // n block
        int row = tid >> 3, c4 = (tid & 7) * 4;
        float4 v = *(const float4*)&W[(size_t)(r0 + row) * D + c0 + c4];
        tile[c4 + 0][row] = f2bf(v.x);
        tile[c4 + 1][row] = f2bf(v.y);
        tile[c4 + 2][row] = f2bf(v.z);
        tile[c4 + 3][row] = f2bf(v.w);
        __syncthreads();
        unsigned int lo = (unsigned int)tile[row][c4] | ((unsigned int)tile[row][c4 + 1] << 16);
        unsigned int hi = (unsigned int)tile[row][c4 + 2] | ((unsigned int)tile[row][c4 + 3] << 16);
        uint2 pk; pk.x = lo; pk.y = hi;
        int n = c0 + row;
        int ct = n >> 4, l15 = n & 15;
        int ks = t & 3;
        int quad = c4 >> 3;
        int j = c4 & 7;
        size_t off = (size_t)m * 16384 + (size_t)(((ct * 4 + ks) * 64) + quad * 16 + l15) * 8 + j;
        *(uint2*)&WT[off] = pk;
    } else {
        int e = ((bx - 64) * 256 + tid) * 4;
        if (e >= E) return;
        if (e + 3 < E) {
            int4 d4 = *(const int4*)&dst[e];
            atomicAdd(&counts[d4.x * CPAD], 1);
            atomicAdd(&counts[d4.y * CPAD], 1);
            atomicAdd(&counts[d4.z * CPAD], 1);
            atomicAdd(&counts[d4.w * CPAD], 1);
        } else {
            for (int i = e; i < E; ++i) atomicAdd(&counts[dst[i] * CPAD], 1);
        }
    }
}

// ---------------- block-local inclusive scan helper ----------------
__device__ __forceinline__ int block_incl_scan256(int v, int tid, int* wsum) {
    int lane = tid & 63;
    int wid = tid >> 6;
#pragma unroll
    for (int off = 1; off < 64; off <<= 1) {
        int t = __shfl_up(v, off, 64);
        if (lane >= off) v += t;
    }
    if (lane == 63) wsum[wid] = v;
    __syncthreads();
#pragma unroll
    for (int w = 0; w < 4; ++w)
        if (w < wid) v += wsum[w];
    return v;
}

// ---------------- merged: segment allocator (blocks < nchunks) + QKV MFMA (rest) ----------------
// Allocator: each block scans its 256 node counts, bumps a global cursor ONCE for its base,
// writes off2[node] = {start, end} AND re-uses counts[node*CPAD] as the scatter write-cursor
// (= start). Segment order across blocks arbitrary — consumers only use per-node [start,end).
// QKV: K and V stored interleaved: KV8[row*256 + 0..127]=K fp8, [128..255]=V fp8.
// LDS staging kept: measured faster than direct-L2 B-fragment reads (round 6: +3-6 µs without).
__global__ __launch_bounds__(256) void alloc_qkv_kernel(
    int* __restrict__ counts, int* __restrict__ cursor, int2* __restrict__ off2,
    int nchunks,
    const float* __restrict__ h, const unsigned short* __restrict__ WT,
    const float* __restrict__ bq, const float* __restrict__ bk, const float* __restrict__ bv,
    unsigned short* __restrict__ Qb, unsigned char* __restrict__ KV8, int n) {
    __shared__ __align__(16) unsigned short wt[16384];   // 32 KB, frag-ordered (QKV path)
    int bx = blockIdx.x;
    int tid = threadIdx.x;
    if (bx < nchunks) {
        __shared__ int wsum[4];
        __shared__ int basesh;
        int i = bx * 256 + tid;
        int c = (i < n) ? counts[i * CPAD] : 0;
        int incl = block_incl_scan256(c, tid, wsum);
        if (tid == 255) basesh = atomicAdd(cursor, incl);
        __syncthreads();
        int start = basesh + incl - c;
        if (i < n) {
            off2[i] = make_int2(start, start + c);
            counts[i * CPAD] = start;          // becomes the scatter write-cursor
        }
        return;
    }
    int bid = bx - nchunks;
    int lane = tid & 63, wave = tid >> 6;
    int quad = lane >> 4, l15 = lane & 15;
    int rt = bid * 64 + wave * 16;

    // A-fragments: h rows rt+l15 (clamped; OOB rows never stored), fp32 -> bf16
    int rowA = min(rt + l15, n - 1);
    bf16x8 af[4];
#pragma unroll
    for (int ks = 0; ks < 4; ++ks) {
        const float* ap = &h[(size_t)rowA * D + ks * 32 + quad * 8];
        float4 a0 = *(const float4*)ap;
        float4 a1 = *(const float4*)(ap + 4);
        union { unsigned short u[8]; bf16x8 v; } pk;
        pk.u[0] = f2bf(a0.x); pk.u[1] = f2bf(a0.y);
        pk.u[2] = f2bf(a0.z); pk.u[3] = f2bf(a0.w);
        pk.u[4] = f2bf(a1.x); pk.u[5] = f2bf(a1.y);
        pk.u[6] = f2bf(a1.z); pk.u[7] = f2bf(a1.w);
        af[ks] = pk.v;
    }

    for (int m = 0; m < 3; ++m) {
        // linear 32 KB copy: lane-consecutive uint4, conflict-free both sides
#pragma unroll
        for (int it = 0; it < 8; ++it) {
            int idx = it * 256 + tid;
            *(uint4*)&wt[idx * 8] = *(const uint4*)&WT[(size_t)m * 16384 + idx * 8];
        }
        __syncthreads();

        f32x4 acc[8];
#pragma unroll
        for (int ct = 0; ct < 8; ++ct) {
            acc[ct] = (f32x4){0.f, 0.f, 0.f, 0.f};
#pragma unroll
            for (int ks = 0; ks < 4; ++ks) {
                bf16x8 bfr = *(const bf16x8*)&wt[((ct * 4 + ks) * 64 + lane) * 8];
                acc[ct] = __builtin_amdgcn_mfma_f32_16x16x32_bf16(af[ks], bfr, acc[ct], 0, 0, 0);
            }
        }
        __syncthreads();   // wt consumed before next m overwrites

        const float* bias = (m == 0) ? bq : (m == 1) ? bk : bv;
#pragma unroll
        for (int ct = 0; ct < 8; ++ct) {
            int col = ct * 16 + l15;
            float bb = bias[col];
#pragma unroll
            for (int r = 0; r < 4; ++r) {
                int row = rt + quad * 4 + r;
                if (row < n) {
                    float v = acc[ct][r] + bb;
                    if (m == 0)      Qb[(size_t)row * D + col] = f2bf(v);
                    else if (m == 1) KV8[(size_t)row * 256 + col] = f2fp8(v);
                    else             KV8[(size_t)row * 256 + 128 + col] = f2fp8(v);
                }
            }
        }
    }
}

// ---------------- scatter: psrc fill, claiming slots via the counts write-cursor ----------------
__global__ __launch_bounds__(256) void scatter_kernel(
    const int* __restrict__ dst, const int* __restrict__ src,
    int* __restrict__ counts, int* __restrict__ psrc, int E) {
    int e = (blockIdx.x * 256 + threadIdx.x) * 4;
    if (e >= E) return;
    if (e + 3 < E) {
        int4 d4 = *(const int4*)&dst[e];
        int4 s4 = *(const int4*)&src[e];
        psrc[atomicAdd(&counts[d4.x * CPAD], 1)] = s4.x;
        psrc[atomicAdd(&counts[d4.y * CPAD], 1)] = s4.y;
        psrc[atomicAdd(&counts[d4.z * CPAD], 1)] = s4.z;
        psrc[atomicAdd(&counts[d4.w * CPAD], 1)] = s4.w;
    } else {
        for (int i = e; i < E; ++i) psrc[atomicAdd(&counts[dst[i] * CPAD], 1)] = src[i];
    }
}

// ---------------- Edge attention (fp8 K/V, interleaved, software-pipelined gather) ----------------
// TWO dst nodes per wave: each 32-lane half owns one node.
// lane%32 = j*8 + hd: j = edge slot (0..3), hd = head (0..7, 16 dims each).
// Bulk-convert form (kf/vf arrays): measured best (round 9's low-VGPR rewrite regressed —
// L3->L2 amplification + serial chain, not TLP, bounds this kernel).
__global__ __launch_bounds__(256) void edge_attn_kernel(
    const unsigned short* __restrict__ Qb, const unsigned char* __restrict__ KV8,
    const int2* __restrict__ off2, const int* __restrict__ psrc,
    unsigned short* __restrict__ aggb, int n) {
    int node = (blockIdx.x * 256 + threadIdx.x) >> 5;
    int l32 = threadIdx.x & 31;
    if (node >= n) return;          // whole 32-lane group exits together
    int2 se = off2[node];
    int start = se.x, end = se.y;
    int j = l32 >> 3, hd = l32 & 7;

    const unsigned short* qp = &Qb[(size_t)node * D + hd * 16];
    uint4 qa = *(const uint4*)qp;
    uint4 qb = *(const uint4*)(qp + 8);
    float q[16];
    q[0] = bf2f_lo(qa.x);  q[1] = bf2f_hi(qa.x);
    q[2] = bf2f_lo(qa.y);  q[3] = bf2f_hi(qa.y);
    q[4] = bf2f_lo(qa.z);  q[5] = bf2f_hi(qa.z);
    q[6] = bf2f_lo(qa.w);  q[7] = bf2f_hi(qa.w);
    q[8] = bf2f_lo(qb.x);  q[9] = bf2f_hi(qb.x);
    q[10] = bf2f_lo(qb.y); q[11] = bf2f_hi(qb.y);
    q[12] = bf2f_lo(qb.z); q[13] = bf2f_hi(qb.z);
    q[14] = bf2f_lo(qb.w); q[15] = bf2f_hi(qb.w);

    float l = 0.f;
    float acc[16] = {};

    if (start < end) {
        int s0 = psrc[min(start + j, end - 1)];
        int s1 = (start + 4 < end) ? psrc[min(start + 4 + j, end - 1)] : 0;
        const unsigned char* kvp = &KV8[(size_t)s0 * 256 + hd * 16];
        uint4 ku = *(const uint4*)kvp;
        uint4 vu = *(const uint4*)(kvp + 128);
        for (int base = start; base < end; base += 4) {
            // issue next iteration's KV loads first (address ready via s1)
            const unsigned char* kvpn = &KV8[(size_t)s1 * 256 + hd * 16];
            uint4 kun = *(const uint4*)kvpn;
            uint4 vun = *(const uint4*)(kvpn + 128);
            // prefetch psrc two iterations ahead
            int s2 = (base + 8 < end) ? psrc[min(base + 8 + j, end - 1)] : 0;
            bool valid = (base + j) < end;

            float kf[16], vf[16];
            {
                f32x2 t;
                t = __builtin_amdgcn_cvt_pk_f32_fp8(ku.x, false); kf[0] = t.x;  kf[1] = t.y;
                t = __builtin_amdgcn_cvt_pk_f32_fp8(ku.x, true);  kf[2] = t.x;  kf[3] = t.y;
                t = __builtin_amdgcn_cvt_pk_f32_fp8(ku.y, false); kf[4] = t.x;  kf[5] = t.y;
                t = __builtin_amdgcn_cvt_pk_f32_fp8(ku.y, true);  kf[6] = t.x;  kf[7] = t.y;
                t = __builtin_amdgcn_cvt_pk_f32_fp8(ku.z, false); kf[8] = t.x;  kf[9] = t.y;
                t = __builtin_amdgcn_cvt_pk_f32_fp8(ku.z, true);  kf[10] = t.x; kf[11] = t.y;
                t = __builtin_amdgcn_cvt_pk_f32_fp8(ku.w, false); kf[12] = t.x; kf[13] = t.y;
                t = __builtin_amdgcn_cvt_pk_f32_fp8(ku.w, true);  kf[14] = t.x; kf[15] = t.y;
                t = __builtin_amdgcn_cvt_pk_f32_fp8(vu.x, false); vf[0] = t.x;  vf[1] = t.y;
                t = __builtin_amdgcn_cvt_pk_f32_fp8(vu.x, true);  vf[2] = t.x;  vf[3] = t.y;
                t = __builtin_amdgcn_cvt_pk_f32_fp8(vu.y, false); vf[4] = t.x;  vf[5] = t.y;
                t = __builtin_amdgcn_cvt_pk_f32_fp8(vu.y, true);  vf[6] = t.x;  vf[7] = t.y;
                t = __builtin_amdgcn_cvt_pk_f32_fp8(vu.z, false); vf[8] = t.x;  vf[9] = t.y;
                t = __builtin_amdgcn_cvt_pk_f32_fp8(vu.z, true);  vf[10] = t.x; vf[11] = t.y;
                t = __builtin_amdgcn_cvt_pk_f32_fp8(vu.w, false); vf[12] = t.x; vf[13] = t.y;
                t = __builtin_amdgcn_cvt_pk_f32_fp8(vu.w, true);  vf[14] = t.x; vf[15] = t.y;
            }

            float sc = q[0] * kf[0];
#pragma unroll
            for (int i = 1; i < 16; ++i) sc = fmaf(q[i], kf[i], sc);

            float p = valid ? __expf(sc) : 0.f;
            l += p;
#pragma unroll
            for (int i = 0; i < 16; ++i) acc[i] = fmaf(p, vf[i], acc[i]);
            ku = kun; vu = vun; s1 = s2;
        }
    }

    // combine the 4 edge slots (lanes differing in bits 3,4 — stays inside the 32-lane node group)
#pragma unroll
    for (int off = 8; off <= 16; off <<= 1) {
        l += __shfl_xor(l, off, 64);
#pragma unroll
        for (int i = 0; i < 16; ++i) acc[i] += __shfl_xor(acc[i], off, 64);
    }
    float inv = (l > 0.f) ? 1.f / l : 0.f;
    if (j == 0) {
        uint4 o0, o1;
        o0.x = (unsigned int)f2bf(acc[0] * inv) | ((unsigned int)f2bf(acc[1] * inv) << 16);
        o0.y = (unsigned int)f2bf(acc[2] * inv) | ((unsigned int)f2bf(acc[3] * inv) << 16);
        o0.z = (unsigned int)f2bf(acc[4] * inv) | ((unsigned int)f2bf(acc[5] * inv) << 16);
        o0.w = (unsigned int)f2bf(acc[6] * inv) | ((unsigned int)f2bf(acc[7] * inv) << 16);
        o1.x = (unsigned int)f2bf(acc[8] * inv) | ((unsigned int)f2bf(acc[9] * inv) << 16);
        o1.y = (unsigned int)f2bf(acc[10] * inv) | ((unsigned int)f2bf(acc[11] * inv) << 16);
        o1.z = (unsigned int)f2bf(acc[12] * inv) | ((unsigned int)f2bf(acc[13] * inv) << 16);
        o1.w = (unsigned int)f2bf(acc[14] * inv) | ((unsigned int)f2bf(acc[15] * inv) << 16);
        unsigned short* op = &aggb[(size_t)node * D + hd * 16];
        *(uint4*)op = o0;
        *(uint4*)(op + 8) = o1;
    }
}

// ---------------- Output GEMM + bias + residual + LayerNorm (frag-ordered WTo, coalesced) ----------------
__global__ __launch_bounds__(256) void out_ln_mfma_kernel(
    const unsigned short* __restrict__ aggb, const unsigned short* __restrict__ WTo,
    const float* __restrict__ bo, const float* __restrict__ hres,
    const float* __restrict__ gamma, const float* __restrict__ beta,
    float* __restrict__ out, int n) {
    int tid = threadIdx.x;
    int lane = tid & 63, wave = tid >> 6;
    int quad = lane >> 4, l15 = lane & 15;
    int rt = blockIdx.x * 64 + wave * 16;

    int rowA = min(rt + l15, n - 1);
    bf16x8 af[4];
#pragma unroll
    for (int ks = 0; ks < 4; ++ks)
        af[ks] = *(const bf16x8*)&aggb[(size_t)rowA * D + ks * 32 + quad * 8];

    f32x4 acc[8];
#pragma unroll
    for (int ct = 0; ct < 8; ++ct) {
        acc[ct] = (f32x4){0.f, 0.f, 0.f, 0.f};
#pragma unroll
        for (int ks = 0; ks < 4; ++ks) {
            bf16x8 bfr = *(const bf16x8*)&WTo[(size_t)((ct * 4 + ks) * 64 + lane) * 8];
            acc[ct] = __builtin_amdgcn_mfma_f32_16x16x32_bf16(af[ks], bfr, acc[ct], 0, 0, 0);
        }
    }

    float bb[8], gg[8], be[8];
#pragma unroll
    for (int ct = 0; ct < 8; ++ct) {
        int col = ct * 16 + l15;
        bb[ct] = bo[col];
        gg[ct] = gamma[col];
        be[ct] = beta[col];
    }
#pragma unroll
    for (int ct = 0; ct < 8; ++ct) {
        int col = ct * 16 + l15;
#pragma unroll
        for (int r = 0; r < 4; ++r) {
            int row = rt + quad * 4 + r;
            float hv = (row < n) ? hres[(size_t)row * D + col] : 0.f;
            acc[ct][r] = acc[ct][r] + bb[ct] + hv;
        }
    }

#pragma unroll
    for (int r = 0; r < 4; ++r) {
        float s1 = 0.f, s2 = 0.f;
#pragma unroll
        for (int ct = 0; ct < 8; ++ct) {
            float v = acc[ct][r];
            s1 += v;
            s2 += v * v;
        }
        s1 += __shfl_xor(s1, 1, 64); s2 += __shfl_xor(s2, 1, 64);
        s1 += __shfl_xor(s1, 2, 64); s2 += __shfl_xor(s2, 2, 64);
        s1 += __shfl_xor(s1, 4, 64); s2 += __shfl_xor(s2, 4, 64);
        s1 += __shfl_xor(s1, 8, 64); s2 += __shfl_xor(s2, 8, 64);
        float mu = s1 * (1.f / 128.f);
        float var = s2 * (1.f / 128.f) - mu * mu;
        float rs = rsqrtf(fmaxf(var, 0.f) + EPS);
        int row = rt + quad * 4 + r;
        if (row < n) {
#pragma unroll
            for (int ct = 0; ct < 8; ++ct) {
                int col = ct * 16 + l15;
                out[(size_t)row * D + col] = (acc[ct][r] - mu) * rs * gg[ct] + be[ct];
            }
        }
    }
}

// ---------------- launch ----------------
extern "C" void kernel_launch(void* const* d_in, const int* in_sizes, int n_in,
                              void* d_out, int out_size, void* d_ws, size_t ws_size,
                              hipStream_t stream) {
    const float* h     = (const float*)d_in[0];
    const float* Wq    = (const float*)d_in[1];
    const float* bq    = (const float*)d_in[2];
    const float* Wk    = (const float*)d_in[3];
    const float* bk    = (const float*)d_in[4];
    const float* Wv    = (const float*)d_in[5];
    const float* bv    = (const float*)d_in[6];
    const float* Wo    = (const float*)d_in[7];
    const float* bo    = (const float*)d_in[8];
    const float* gamma = (const float*)d_in[9];
    const float* beta  = (const float*)d_in[10];
    const int* src     = (const int*)d_in[11];
    const int* dst     = (const int*)d_in[12];
    float* out = (float*)d_out;

    int N = in_sizes[0] / D;
    int E = in_sizes[11];

    // workspace layout
    unsigned short* Qb = (unsigned short*)d_ws;               // N*D bf16
    unsigned short* Ab = Qb + (size_t)N * D;                  // N*D bf16
    unsigned short* WT = Ab + (size_t)N * D;                  // 4*D*D bf16 (frag order)
    unsigned char* KV8 = (unsigned char*)(WT + 4 * D * D);    // N*256 fp8 (K|V interleaved)
    int* counts   = (int*)(KV8 + (size_t)N * 256);            // N*CPAD (counts, then scatter cursor)
    int* cursor   = counts + (size_t)N * CPAD;                // 16 ints (zeroed with counts)
    int2* off2    = (int2*)(cursor + 16);                     // N {start,end}
    int* psrc     = (int*)(off2 + N);                         // E

    int nchunks = (N + 255) / 256;
    int e4blocks = ((E + 3) / 4 + 255) / 256;
    int nqkv = (N + 63) / 64;

    hipMemsetAsync(counts, 0, ((size_t)N * CPAD + 16) * sizeof(int), stream);
    prep_kernel<<<64 + e4blocks, 256, 0, stream>>>(Wq, Wk, Wv, Wo, WT, dst, counts, E);
    alloc_qkv_kernel<<<nchunks + nqkv, 256, 0, stream>>>(
        counts, cursor, off2, nchunks, h, WT, bq, bk, bv, Qb, KV8, N);
    scatter_kernel<<<e4blocks, 256, 0, stream>>>(dst, src, counts, psrc, E);
    edge_attn_kernel<<<(N + 7) / 8, 256, 0, stream>>>(Qb, KV8, off2, psrc, Ab, N);
    out_ln_mfma_kernel<<<(N + 63) / 64, 256, 0, stream>>>(Ab, WT + 3 * D * D, bo, h, gamma, beta, out, N);
}

// Round 11
// 218.405 us; speedup vs baseline: 1.1669x; 1.1669x over previous
//
#include <hip/hip_runtime.h>
#include <hip/hip_bf16.h>
#include <math.h>

#define D 128
#define EPS 1e-12f
#define CPAD 16   // one counter per 64B cache line: kills same-line atomic serialization

typedef __attribute__((ext_vector_type(8))) short bf16x8;
typedef __attribute__((ext_vector_type(4))) float f32x4;
typedef __attribute__((ext_vector_type(2))) float f32x2;

// float -> bf16 round-to-nearest-even (finite inputs)
__device__ __forceinline__ unsigned short f2bf(float f) {
    unsigned int u = __float_as_uint(f);
    return (unsigned short)((u + 0x7fffu + ((u >> 16) & 1u)) >> 16);
}
__device__ __forceinline__ float bf2f_lo(unsigned int packed) {
    return __uint_as_float(packed << 16);
}
__device__ __forceinline__ float bf2f_hi(unsigned int packed) {
    return __uint_as_float(packed & 0xffff0000u);
}
__device__ __forceinline__ unsigned char f2fp8(float f) {
    return (unsigned char)__builtin_amdgcn_cvt_pk_fp8_f32(f, f, 0, false);
}

// ---------------- merged: W convert to MFMA-fragment order (blocks 0..63) + ticket ----------------
// Fragment order: WT[m*16384 + ((ct*4+ks)*64 + quad*16 + l15)*8 + j]
//   holds element (n = ct*16+l15, k = ks*32+quad*8+j) of W_m^T  (bf16)
// Ticket atomics live HERE (overlapped with W-conv, coalesced ticket store) — moving them
// into scatter (round 10) tripled scatter's time via the dependent atomic->store chain.
__global__ __launch_bounds__(256) void prep_kernel(
    const float* __restrict__ Wq, const float* __restrict__ Wk,
    const float* __restrict__ Wv, const float* __restrict__ Wo,
    unsigned short* __restrict__ WT,
    const int* __restrict__ dst, int* __restrict__ counts,
    int* __restrict__ ticket, int E) {
    int bx = blockIdx.x;
    int tid = threadIdx.x;
    if (bx < 64) {
        __shared__ unsigned short tile[32][33];
        int m = bx >> 4;
        int t = bx & 15;
        const float* W = (m == 0) ? Wq : (m == 1) ? Wk : (m == 2) ? Wv : Wo;
        int r0 = (t & 3) * 32;   // k block
        int c0 = (t >> 2) * 32;  // n block
        int row = tid >> 3, c4 = (tid & 7) * 4;
        float4 v = *(const float4*)&W[(size_t)(r0 + row) * D + c0 + c4];
        tile[c4 + 0][row] = f2bf(v.x);
        tile[c4 + 1][row] = f2bf(v.y);
        tile[c4 + 2][row] = f2bf(v.z);
        tile[c4 + 3][row] = f2bf(v.w);
        __syncthreads();
        unsigned int lo = (unsigned int)tile[row][c4] | ((unsigned int)tile[row][c4 + 1] << 16);
        unsigned int hi = (unsigned int)tile[row][c4 + 2] | ((unsigned int)tile[row][c4 + 3] << 16);
        uint2 pk; pk.x = lo; pk.y = hi;
        int n = c0 + row;
        int ct = n >> 4, l15 = n & 15;
        int ks = t & 3;
        int quad = c4 >> 3;
        int j = c4 & 7;
        size_t off = (size_t)m * 16384 + (size_t)(((ct * 4 + ks) * 64) + quad * 16 + l15) * 8 + j;
        *(uint2*)&WT[off] = pk;
    } else {
        int e = ((bx - 64) * 256 + tid) * 4;
        if (e >= E) return;
        if (e + 3 < E) {
            int4 d4 = *(const int4*)&dst[e];
            int4 t4;
            t4.x = atomicAdd(&counts[d4.x * CPAD], 1);
            t4.y = atomicAdd(&counts[d4.y * CPAD], 1);
            t4.z = atomicAdd(&counts[d4.z * CPAD], 1);
            t4.w = atomicAdd(&counts[d4.w * CPAD], 1);
            *(int4*)&ticket[e] = t4;
        } else {
            for (int i = e; i < E; ++i) ticket[i] = atomicAdd(&counts[dst[i] * CPAD], 1);
        }
    }
}

// ---------------- block-local inclusive scan helper ----------------
__device__ __forceinline__ int block_incl_scan256(int v, int tid, int* wsum) {
    int lane = tid & 63;
    int wid = tid >> 6;
#pragma unroll
    for (int off = 1; off < 64; off <<= 1) {
        int t = __shfl_up(v, off, 64);
        if (lane >= off) v += t;
    }
    if (lane == 63) wsum[wid] = v;
    __syncthreads();
#pragma unroll
    for (int w = 0; w < 4; ++w)
        if (w < wid) v += wsum[w];
    return v;
}

// ---------------- merged: segment allocator (blocks < nchunks) + QKV MFMA (rest) ----------------
// Allocator: each block scans its 256 node counts, bumps a global cursor ONCE for its base,
// writes off2[node] = {start, end}. Segment order across blocks arbitrary — consumers only
// use per-node [start,end), so semantics unchanged.
// QKV: K and V stored interleaved: KV8[row*256 + 0..127]=K fp8, [128..255]=V fp8.
// LDS staging kept: measured faster than direct-L2 B-fragment reads (round 6: +3-6 µs without).
__global__ __launch_bounds__(256) void alloc_qkv_kernel(
    const int* __restrict__ counts, int* __restrict__ cursor, int2* __restrict__ off2,
    int nchunks,
    const float* __restrict__ h, const unsigned short* __restrict__ WT,
    const float* __restrict__ bq, const float* __restrict__ bk, const float* __restrict__ bv,
    unsigned short* __restrict__ Qb, unsigned char* __restrict__ KV8, int n) {
    __shared__ __align__(16) unsigned short wt[16384];   // 32 KB, frag-ordered (QKV path)
    int bx = blockIdx.x;
    int tid = threadIdx.x;
    if (bx < nchunks) {
        __shared__ int wsum[4];
        __shared__ int basesh;
        int i = bx * 256 + tid;
        int c = (i < n) ? counts[i * CPAD] : 0;
        int incl = block_incl_scan256(c, tid, wsum);
        if (tid == 255) basesh = atomicAdd(cursor, incl);
        __syncthreads();
        int start = basesh + incl - c;
        if (i < n) off2[i] = make_int2(start, start + c);
        return;
    }
    int bid = bx - nchunks;
    int lane = tid & 63, wave = tid >> 6;
    int quad = lane >> 4, l15 = lane & 15;
    int rt = bid * 64 + wave * 16;

    // A-fragments: h rows rt+l15 (clamped; OOB rows never stored), fp32 -> bf16
    int rowA = min(rt + l15, n - 1);
    bf16x8 af[4];
#pragma unroll
    for (int ks = 0; ks < 4; ++ks) {
        const float* ap = &h[(size_t)rowA * D + ks * 32 + quad * 8];
        float4 a0 = *(const float4*)ap;
        float4 a1 = *(const float4*)(ap + 4);
        union { unsigned short u[8]; bf16x8 v; } pk;
        pk.u[0] = f2bf(a0.x); pk.u[1] = f2bf(a0.y);
        pk.u[2] = f2bf(a0.z); pk.u[3] = f2bf(a0.w);
        pk.u[4] = f2bf(a1.x); pk.u[5] = f2bf(a1.y);
        pk.u[6] = f2bf(a1.z); pk.u[7] = f2bf(a1.w);
        af[ks] = pk.v;
    }

    for (int m = 0; m < 3; ++m) {
        // linear 32 KB copy: lane-consecutive uint4, conflict-free both sides
#pragma unroll
        for (int it = 0; it < 8; ++it) {
            int idx = it * 256 + tid;
            *(uint4*)&wt[idx * 8] = *(const uint4*)&WT[(size_t)m * 16384 + idx * 8];
        }
        __syncthreads();

        f32x4 acc[8];
#pragma unroll
        for (int ct = 0; ct < 8; ++ct) {
            acc[ct] = (f32x4){0.f, 0.f, 0.f, 0.f};
#pragma unroll
            for (int ks = 0; ks < 4; ++ks) {
                bf16x8 bfr = *(const bf16x8*)&wt[((ct * 4 + ks) * 64 + lane) * 8];
                acc[ct] = __builtin_amdgcn_mfma_f32_16x16x32_bf16(af[ks], bfr, acc[ct], 0, 0, 0);
            }
        }
        __syncthreads();   // wt consumed before next m overwrites

        const float* bias = (m == 0) ? bq : (m == 1) ? bk : bv;
#pragma unroll
        for (int ct = 0; ct < 8; ++ct) {
            int col = ct * 16 + l15;
            float bb = bias[col];
#pragma unroll
            for (int r = 0; r < 4; ++r) {
                int row = rt + quad * 4 + r;
                if (row < n) {
                    float v = acc[ct][r] + bb;
                    if (m == 0)      Qb[(size_t)row * D + col] = f2bf(v);
                    else if (m == 1) KV8[(size_t)row * 256 + col] = f2fp8(v);
                    else             KV8[(size_t)row * 256 + 128 + col] = f2fp8(v);
                }
            }
        }
    }
}

// ---------------- scatter: psrc fill using allocator bases + prep tickets ----------------
__global__ __launch_bounds__(256) void scatter_kernel(
    const int* __restrict__ dst, const int* __restrict__ src,
    const int* __restrict__ ticket, const int2* __restrict__ off2,
    int* __restrict__ psrc, int E) {
    int e = (blockIdx.x * 256 + threadIdx.x) * 4;
    if (e >= E) return;
    if (e + 3 < E) {
        int4 d4 = *(const int4*)&dst[e];
        int4 s4 = *(const int4*)&src[e];
        int4 t4 = *(const int4*)&ticket[e];
        psrc[off2[d4.x].x + t4.x] = s4.x;
        psrc[off2[d4.y].x + t4.y] = s4.y;
        psrc[off2[d4.z].x + t4.z] = s4.z;
        psrc[off2[d4.w].x + t4.w] = s4.w;
    } else {
        for (int i = e; i < E; ++i) psrc[off2[dst[i]].x + ticket[i]] = src[i];
    }
}

// ---------------- Edge attention (fp8 K/V, interleaved, depth-2 pipelined gather) ----------------
// TWO dst nodes per wave: each 32-lane half owns one node.
// lane%32 = j*8 + hd: j = edge slot (0..3), hd = head (0..7, 16 dims each).
// Bulk-convert form (kf/vf arrays): measured best (round 9's convert-and-consume regressed).
// Depth-2 KV pipeline: two line-pairs in flight (+8 VGPR, same occupancy band <128).
__global__ __launch_bounds__(256) void edge_attn_kernel(
    const unsigned short* __restrict__ Qb, const unsigned char* __restrict__ KV8,
    const int2* __restrict__ off2, const int* __restrict__ psrc,
    unsigned short* __restrict__ aggb, int n) {
    int node = (blockIdx.x * 256 + threadIdx.x) >> 5;
    int l32 = threadIdx.x & 31;
    if (node >= n) return;          // whole 32-lane group exits together
    int2 se = off2[node];
    int start = se.x, end = se.y;
    int j = l32 >> 3, hd = l32 & 7;

    const unsigned short* qp = &Qb[(size_t)node * D + hd * 16];
    uint4 qa = *(const uint4*)qp;
    uint4 qb = *(const uint4*)(qp + 8);
    float q[16];
    q[0] = bf2f_lo(qa.x);  q[1] = bf2f_hi(qa.x);
    q[2] = bf2f_lo(qa.y);  q[3] = bf2f_hi(qa.y);
    q[4] = bf2f_lo(qa.z);  q[5] = bf2f_hi(qa.z);
    q[6] = bf2f_lo(qa.w);  q[7] = bf2f_hi(qa.w);
    q[8] = bf2f_lo(qb.x);  q[9] = bf2f_hi(qb.x);
    q[10] = bf2f_lo(qb.y); q[11] = bf2f_hi(qb.y);
    q[12] = bf2f_lo(qb.z); q[13] = bf2f_hi(qb.z);
    q[14] = bf2f_lo(qb.w); q[15] = bf2f_hi(qb.w);

    float l = 0.f;
    float acc[16] = {};

    if (start < end) {
        int s0 = psrc[min(start + j, end - 1)];
        int s1 = (start + 4 < end) ? psrc[min(start + 4 + j, end - 1)] : 0;
        int s2 = (start + 8 < end) ? psrc[min(start + 8 + j, end - 1)] : 0;
        const unsigned char* p0 = &KV8[(size_t)s0 * 256 + hd * 16];
        uint4 ku0 = *(const uint4*)p0;
        uint4 vu0 = *(const uint4*)(p0 + 128);
        const unsigned char* p1 = &KV8[(size_t)s1 * 256 + hd * 16];
        uint4 ku1 = *(const uint4*)p1;
        uint4 vu1 = *(const uint4*)(p1 + 128);
        for (int base = start; base < end; base += 4) {
            // issue KV loads two iterations ahead (address ready via s2)
            const unsigned char* p2 = &KV8[(size_t)s2 * 256 + hd * 16];
            uint4 ku2 = *(const uint4*)p2;
            uint4 vu2 = *(const uint4*)(p2 + 128);
            // prefetch psrc three iterations ahead
            int s3 = (base + 12 < end) ? psrc[min(base + 12 + j, end - 1)] : 0;
            bool valid = (base + j) < end;

            float kf[16], vf[16];
            {
                f32x2 t;
                t = __builtin_amdgcn_cvt_pk_f32_fp8(ku0.x, false); kf[0] = t.x;  kf[1] = t.y;
                t = __builtin_amdgcn_cvt_pk_f32_fp8(ku0.x, true);  kf[2] = t.x;  kf[3] = t.y;
                t = __builtin_amdgcn_cvt_pk_f32_fp8(ku0.y, false); kf[4] = t.x;  kf[5] = t.y;
                t = __builtin_amdgcn_cvt_pk_f32_fp8(ku0.y, true);  kf[6] = t.x;  kf[7] = t.y;
                t = __builtin_amdgcn_cvt_pk_f32_fp8(ku0.z, false); kf[8] = t.x;  kf[9] = t.y;
                t = __builtin_amdgcn_cvt_pk_f32_fp8(ku0.z, true);  kf[10] = t.x; kf[11] = t.y;
                t = __builtin_amdgcn_cvt_pk_f32_fp8(ku0.w, false); kf[12] = t.x; kf[13] = t.y;
                t = __builtin_amdgcn_cvt_pk_f32_fp8(ku0.w, true);  kf[14] = t.x; kf[15] = t.y;
                t = __builtin_amdgcn_cvt_pk_f32_fp8(vu0.x, false); vf[0] = t.x;  vf[1] = t.y;
                t = __builtin_amdgcn_cvt_pk_f32_fp8(vu0.x, true);  vf[2] = t.x;  vf[3] = t.y;
                t = __builtin_amdgcn_cvt_pk_f32_fp8(vu0.y, false); vf[4] = t.x;  vf[5] = t.y;
                t = __builtin_amdgcn_cvt_pk_f32_fp8(vu0.y, true);  vf[6] = t.x;  vf[7] = t.y;
                t = __builtin_amdgcn_cvt_pk_f32_fp8(vu0.z, false); vf[8] = t.x;  vf[9] = t.y;
                t = __builtin_amdgcn_cvt_pk_f32_fp8(vu0.z, true);  vf[10] = t.x; vf[11] = t.y;
                t = __builtin_amdgcn_cvt_pk_f32_fp8(vu0.w, false); vf[12] = t.x; vf[13] = t.y;
                t = __builtin_amdgcn_cvt_pk_f32_fp8(vu0.w, true);  vf[14] = t.x; vf[15] = t.y;
            }

            float sc = q[0] * kf[0];
#pragma unroll
            for (int i = 1; i < 16; ++i) sc = fmaf(q[i], kf[i], sc);

            float p = valid ? __expf(sc) : 0.f;
            l += p;
#pragma unroll
            for (int i = 0; i < 16; ++i) acc[i] = fmaf(p, vf[i], acc[i]);
            ku0 = ku1; vu0 = vu1; ku1 = ku2; vu1 = vu2; s2 = s3;
        }
    }

    // combine the 4 edge slots (lanes differing in bits 3,4 — stays inside the 32-lane node group)
#pragma unroll
    for (int off = 8; off <= 16; off <<= 1) {
        l += __shfl_xor(l, off, 64);
#pragma unroll
        for (int i = 0; i < 16; ++i) acc[i] += __shfl_xor(acc[i], off, 64);
    }
    float inv = (l > 0.f) ? 1.f / l : 0.f;
    if (j == 0) {
        uint4 o0, o1;
        o0.x = (unsigned int)f2bf(acc[0] * inv) | ((unsigned int)f2bf(acc[1] * inv) << 16);
        o0.y = (unsigned int)f2bf(acc[2] * inv) | ((unsigned int)f2bf(acc[3] * inv) << 16);
        o0.z = (unsigned int)f2bf(acc[4] * inv) | ((unsigned int)f2bf(acc[5] * inv) << 16);
        o0.w = (unsigned int)f2bf(acc[6] * inv) | ((unsigned int)f2bf(acc[7] * inv) << 16);
        o1.x = (unsigned int)f2bf(acc[8] * inv) | ((unsigned int)f2bf(acc[9] * inv) << 16);
        o1.y = (unsigned int)f2bf(acc[10] * inv) | ((unsigned int)f2bf(acc[11] * inv) << 16);
        o1.z = (unsigned int)f2bf(acc[12] * inv) | ((unsigned int)f2bf(acc[13] * inv) << 16);
        o1.w = (unsigned int)f2bf(acc[14] * inv) | ((unsigned int)f2bf(acc[15] * inv) << 16);
        unsigned short* op = &aggb[(size_t)node * D + hd * 16];
        *(uint4*)op = o0;
        *(uint4*)(op + 8) = o1;
    }
}

// ---------------- Output GEMM + bias + residual + LayerNorm (frag-ordered WTo, coalesced) ----------------
__global__ __launch_bounds__(256) void out_ln_mfma_kernel(
    const unsigned short* __restrict__ aggb, const unsigned short* __restrict__ WTo,
    const float* __restrict__ bo, const float* __restrict__ hres,
    const float* __restrict__ gamma, const float* __restrict__ beta,
    float* __restrict__ out, int n) {
    int tid = threadIdx.x;
    int lane = tid & 63, wave = tid >> 6;
    int quad = lane >> 4, l15 = lane & 15;
    int rt = blockIdx.x * 64 + wave * 16;

    int rowA = min(rt + l15, n - 1);
    bf16x8 af[4];
#pragma unroll
    for (int ks = 0; ks < 4; ++ks)
        af[ks] = *(const bf16x8*)&aggb[(size_t)rowA * D + ks * 32 + quad * 8];

    f32x4 acc[8];
#pragma unroll
    for (int ct = 0; ct < 8; ++ct) {
        acc[ct] = (f32x4){0.f, 0.f, 0.f, 0.f};
#pragma unroll
        for (int ks = 0; ks < 4; ++ks) {
            bf16x8 bfr = *(const bf16x8*)&WTo[(size_t)((ct * 4 + ks) * 64 + lane) * 8];
            acc[ct] = __builtin_amdgcn_mfma_f32_16x16x32_bf16(af[ks], bfr, acc[ct], 0, 0, 0);
        }
    }

    float bb[8], gg[8], be[8];
#pragma unroll
    for (int ct = 0; ct < 8; ++ct) {
        int col = ct * 16 + l15;
        bb[ct] = bo[col];
        gg[ct] = gamma[col];
        be[ct] = beta[col];
    }
#pragma unroll
    for (int ct = 0; ct < 8; ++ct) {
        int col = ct * 16 + l15;
#pragma unroll
        for (int r = 0; r < 4; ++r) {
            int row = rt + quad * 4 + r;
            float hv = (row < n) ? hres[(size_t)row * D + col] : 0.f;
            acc[ct][r] = acc[ct][r] + bb[ct] + hv;
        }
    }

#pragma unroll
    for (int r = 0; r < 4; ++r) {
        float s1 = 0.f, s2 = 0.f;
#pragma unroll
        for (int ct = 0; ct < 8; ++ct) {
            float v = acc[ct][r];
            s1 += v;
            s2 += v * v;
        }
        s1 += __shfl_xor(s1, 1, 64); s2 += __shfl_xor(s2, 1, 64);
        s1 += __shfl_xor(s1, 2, 64); s2 += __shfl_xor(s2, 2, 64);
        s1 += __shfl_xor(s1, 4, 64); s2 += __shfl_xor(s2, 4, 64);
        s1 += __shfl_xor(s1, 8, 64); s2 += __shfl_xor(s2, 8, 64);
        float mu = s1 * (1.f / 128.f);
        float var = s2 * (1.f / 128.f) - mu * mu;
        float rs = rsqrtf(fmaxf(var, 0.f) + EPS);
        int row = rt + quad * 4 + r;
        if (row < n) {
#pragma unroll
            for (int ct = 0; ct < 8; ++ct) {
                int col = ct * 16 + l15;
                out[(size_t)row * D + col] = (acc[ct][r] - mu) * rs * gg[ct] + be[ct];
            }
        }
    }
}

// ---------------- launch ----------------
extern "C" void kernel_launch(void* const* d_in, const int* in_sizes, int n_in,
                              void* d_out, int out_size, void* d_ws, size_t ws_size,
                              hipStream_t stream) {
    const float* h     = (const float*)d_in[0];
    const float* Wq    = (const float*)d_in[1];
    const float* bq    = (const float*)d_in[2];
    const float* Wk    = (const float*)d_in[3];
    const float* bk    = (const float*)d_in[4];
    const float* Wv    = (const float*)d_in[5];
    const float* bv    = (const float*)d_in[6];
    const float* Wo    = (const float*)d_in[7];
    const float* bo    = (const float*)d_in[8];
    const float* gamma = (const float*)d_in[9];
    const float* beta  = (const float*)d_in[10];
    const int* src     = (const int*)d_in[11];
    const int* dst     = (const int*)d_in[12];
    float* out = (float*)d_out;

    int N = in_sizes[0] / D;
    int E = in_sizes[11];

    // workspace layout
    unsigned short* Qb = (unsigned short*)d_ws;               // N*D bf16
    unsigned short* Ab = Qb + (size_t)N * D;                  // N*D bf16
    unsigned short* WT = Ab + (size_t)N * D;                  // 4*D*D bf16 (frag order)
    unsigned char* KV8 = (unsigned char*)(WT + 4 * D * D);    // N*256 fp8 (K|V interleaved)
    int* counts   = (int*)(KV8 + (size_t)N * 256);            // N*CPAD (padded, 1/line)
    int* cursor   = counts + (size_t)N * CPAD;                // 16 ints (zeroed with counts)
    int2* off2    = (int2*)(cursor + 16);                     // N {start,end}
    int* ticket   = (int*)(off2 + N);                         // E
    int* psrc     = ticket + E;                               // E

    int nchunks = (N + 255) / 256;
    int e4blocks = ((E + 3) / 4 + 255) / 256;
    int nqkv = (N + 63) / 64;

    hipMemsetAsync(counts, 0, ((size_t)N * CPAD + 16) * sizeof(int), stream);
    prep_kernel<<<64 + e4blocks, 256, 0, stream>>>(Wq, Wk, Wv, Wo, WT, dst, counts, ticket, E);
    alloc_qkv_kernel<<<nchunks + nqkv, 256, 0, stream>>>(
        counts, cursor, off2, nchunks, h, WT, bq, bk, bv, Qb, KV8, N);
    scatter_kernel<<<e4blocks, 256, 0, stream>>>(dst, src, ticket, off2, psrc, E);
    edge_attn_kernel<<<(N + 7) / 8, 256, 0, stream>>>(Qb, KV8, off2, psrc, Ab, N);
    out_ln_mfma_kernel<<<(N + 63) / 64, 256, 0, stream>>>(Ab, WT + 3 * D * D, bo, h, gamma, beta, out, N);
}

// Round 12
// 218.402 us; speedup vs baseline: 1.1669x; 1.0000x over previous
//
#include <hip/hip_runtime.h>
#include <hip/hip_bf16.h>
#include <math.h>

#define D 128
#define EPS 1e-12f
#define CPAD 16   // one counter per 64B cache line: kills same-line atomic serialization

typedef __attribute__((ext_vector_type(8))) short bf16x8;
typedef __attribute__((ext_vector_type(4))) float f32x4;
typedef __attribute__((ext_vector_type(2))) float f32x2;

// float -> bf16 round-to-nearest-even (finite inputs)
__device__ __forceinline__ unsigned short f2bf(float f) {
    unsigned int u = __float_as_uint(f);
    return (unsigned short)((u + 0x7fffu + ((u >> 16) & 1u)) >> 16);
}
__device__ __forceinline__ float bf2f_lo(unsigned int packed) {
    return __uint_as_float(packed << 16);
}
__device__ __forceinline__ float bf2f_hi(unsigned int packed) {
    return __uint_as_float(packed & 0xffff0000u);
}
__device__ __forceinline__ unsigned char f2fp8(float f) {
    return (unsigned char)__builtin_amdgcn_cvt_pk_fp8_f32(f, f, 0, false);
}

// ---------------- merged: W convert to MFMA-fragment order (blocks 0..63) + ticket ----------------
// Fragment order: WT[m*16384 + ((ct*4+ks)*64 + quad*16 + l15)*8 + j]
//   holds element (n = ct*16+l15, k = ks*32+quad*8+j) of W_m^T  (bf16)
// Ticket atomics live HERE (overlapped with W-conv, coalesced ticket store) — moving them
// into scatter (round 10) tripled scatter's time via the dependent atomic->store chain.
__global__ __launch_bounds__(256) void prep_kernel(
    const float* __restrict__ Wq, const float* __restrict__ Wk,
    const float* __restrict__ Wv, const float* __restrict__ Wo,
    unsigned short* __restrict__ WT,
    const int* __restrict__ dst, int* __restrict__ counts,
    int* __restrict__ ticket, int E) {
    int bx = blockIdx.x;
    int tid = threadIdx.x;
    if (bx < 64) {
        __shared__ unsigned short tile[32][33];
        int m = bx >> 4;
        int t = bx & 15;
        const float* W = (m == 0) ? Wq : (m == 1) ? Wk : (m == 2) ? Wv : Wo;
        int r0 = (t & 3) * 32;   // k block
        int c0 = (t >> 2) * 32;  // n block
        int row = tid >> 3, c4 = (tid & 7) * 4;
        float4 v = *(const float4*)&W[(size_t)(r0 + row) * D + c0 + c4];
        tile[c4 + 0][row] = f2bf(v.x);
        tile[c4 + 1][row] = f2bf(v.y);
        tile[c4 + 2][row] = f2bf(v.z);
        tile[c4 + 3][row] = f2bf(v.w);
        __syncthreads();
        unsigned int lo = (unsigned int)tile[row][c4] | ((unsigned int)tile[row][c4 + 1] << 16);
        unsigned int hi = (unsigned int)tile[row][c4 + 2] | ((unsigned int)tile[row][c4 + 3] << 16);
        uint2 pk; pk.x = lo; pk.y = hi;
        int n = c0 + row;
        int ct = n >> 4, l15 = n & 15;
        int ks = t & 3;
        int quad = c4 >> 3;
        int j = c4 & 7;
        size_t off = (size_t)m * 16384 + (size_t)(((ct * 4 + ks) * 64) + quad * 16 + l15) * 8 + j;
        *(uint2*)&WT[off] = pk;
    } else {
        int e = ((bx - 64) * 256 + tid) * 4;
        if (e >= E) return;
        if (e + 3 < E) {
            int4 d4 = *(const int4*)&dst[e];
            int4 t4;
            t4.x = atomicAdd(&counts[d4.x * CPAD], 1);
            t4.y = atomicAdd(&counts[d4.y * CPAD], 1);
            t4.z = atomicAdd(&counts[d4.z * CPAD], 1);
            t4.w = atomicAdd(&counts[d4.w * CPAD], 1);
            *(int4*)&ticket[e] = t4;
        } else {
            for (int i = e; i < E; ++i) ticket[i] = atomicAdd(&counts[dst[i] * CPAD], 1);
        }
    }
}

// ---------------- block-local inclusive scan helper ----------------
__device__ __forceinline__ int block_incl_scan256(int v, int tid, int* wsum) {
    int lane = tid & 63;
    int wid = tid >> 6;
#pragma unroll
    for (int off = 1; off < 64; off <<= 1) {
        int t = __shfl_up(v, off, 64);
        if (lane >= off) v += t;
    }
    if (lane == 63) wsum[wid] = v;
    __syncthreads();
#pragma unroll
    for (int w = 0; w < 4; ++w)
        if (w < wid) v += wsum[w];
    return v;
}

// ---------------- segment allocator (tiny dispatch: nchunks blocks) ----------------
// Each block scans its 256 node counts, bumps a global cursor ONCE for its base,
// writes off2[node] = {start, end}. Segment order across blocks arbitrary — consumers
// only use per-node [start,end), so semantics unchanged.
__global__ __launch_bounds__(256) void alloc_kernel(
    const int* __restrict__ counts, int* __restrict__ cursor, int2* __restrict__ off2, int n) {
    __shared__ int wsum[4];
    __shared__ int basesh;
    int tid = threadIdx.x;
    int i = blockIdx.x * 256 + tid;
    int c = (i < n) ? counts[i * CPAD] : 0;
    int incl = block_incl_scan256(c, tid, wsum);
    if (tid == 255) basesh = atomicAdd(cursor, incl);
    __syncthreads();
    int start = basesh + incl - c;
    if (i < n) off2[i] = make_int2(start, start + c);
}

// ---------------- merged: scatter (blocks < e4blocks) + QKV MFMA (rest) ----------------
// Scatter (pure latency-bound, VALUBusy <1%) co-dispatches with the QKV MFMA blocks so its
// exposed pointer-chase latency hides under QKV's compute on other waves/CUs.
// QKV: K and V stored interleaved: KV8[row*256 + 0..127]=K fp8, [128..255]=V fp8.
// LDS staging kept: measured faster than direct-L2 B-fragment reads (round 6: +3-6 µs without).
__global__ __launch_bounds__(256) void scatter_qkv_kernel(
    const int* __restrict__ dst, const int* __restrict__ src,
    const int* __restrict__ ticket, const int2* __restrict__ off2,
    int* __restrict__ psrc, int E, int e4blocks,
    const float* __restrict__ h, const unsigned short* __restrict__ WT,
    const float* __restrict__ bq, const float* __restrict__ bk, const float* __restrict__ bv,
    unsigned short* __restrict__ Qb, unsigned char* __restrict__ KV8, int n) {
    __shared__ __align__(16) unsigned short wt[16384];   // 32 KB, frag-ordered (QKV path)
    int bx = blockIdx.x;
    int tid = threadIdx.x;
    if (bx < e4blocks) {
        int e = (bx * 256 + tid) * 4;
        if (e >= E) return;
        if (e + 3 < E) {
            int4 d4 = *(const int4*)&dst[e];
            int4 s4 = *(const int4*)&src[e];
            int4 t4 = *(const int4*)&ticket[e];
            psrc[off2[d4.x].x + t4.x] = s4.x;
            psrc[off2[d4.y].x + t4.y] = s4.y;
            psrc[off2[d4.z].x + t4.z] = s4.z;
            psrc[off2[d4.w].x + t4.w] = s4.w;
        } else {
            for (int i = e; i < E; ++i) psrc[off2[dst[i]].x + ticket[i]] = src[i];
        }
        return;
    }
    int bid = bx - e4blocks;
    int lane = tid & 63, wave = tid >> 6;
    int quad = lane >> 4, l15 = lane & 15;
    int rt = bid * 64 + wave * 16;

    // A-fragments: h rows rt+l15 (clamped; OOB rows never stored), fp32 -> bf16
    int rowA = min(rt + l15, n - 1);
    bf16x8 af[4];
#pragma unroll
    for (int ks = 0; ks < 4; ++ks) {
        const float* ap = &h[(size_t)rowA * D + ks * 32 + quad * 8];
        float4 a0 = *(const float4*)ap;
        float4 a1 = *(const float4*)(ap + 4);
        union { unsigned short u[8]; bf16x8 v; } pk;
        pk.u[0] = f2bf(a0.x); pk.u[1] = f2bf(a0.y);
        pk.u[2] = f2bf(a0.z); pk.u[3] = f2bf(a0.w);
        pk.u[4] = f2bf(a1.x); pk.u[5] = f2bf(a1.y);
        pk.u[6] = f2bf(a1.z); pk.u[7] = f2bf(a1.w);
        af[ks] = pk.v;
    }

    for (int m = 0; m < 3; ++m) {
        // linear 32 KB copy: lane-consecutive uint4, conflict-free both sides
#pragma unroll
        for (int it = 0; it < 8; ++it) {
            int idx = it * 256 + tid;
            *(uint4*)&wt[idx * 8] = *(const uint4*)&WT[(size_t)m * 16384 + idx * 8];
        }
        __syncthreads();

        f32x4 acc[8];
#pragma unroll
        for (int ct = 0; ct < 8; ++ct) {
            acc[ct] = (f32x4){0.f, 0.f, 0.f, 0.f};
#pragma unroll
            for (int ks = 0; ks < 4; ++ks) {
                bf16x8 bfr = *(const bf16x8*)&wt[((ct * 4 + ks) * 64 + lane) * 8];
                acc[ct] = __builtin_amdgcn_mfma_f32_16x16x32_bf16(af[ks], bfr, acc[ct], 0, 0, 0);
            }
        }
        __syncthreads();   // wt consumed before next m overwrites

        const float* bias = (m == 0) ? bq : (m == 1) ? bk : bv;
#pragma unroll
        for (int ct = 0; ct < 8; ++ct) {
            int col = ct * 16 + l15;
            float bb = bias[col];
#pragma unroll
            for (int r = 0; r < 4; ++r) {
                int row = rt + quad * 4 + r;
                if (row < n) {
                    float v = acc[ct][r] + bb;
                    if (m == 0)      Qb[(size_t)row * D + col] = f2bf(v);
                    else if (m == 1) KV8[(size_t)row * 256 + col] = f2fp8(v);
                    else             KV8[(size_t)row * 256 + 128 + col] = f2fp8(v);
                }
            }
        }
    }
}

// ---------------- Edge attention (fp8 K/V, interleaved, depth-1 pipelined gather) ----------------
// TWO dst nodes per wave: each 32-lane half owns one node.
// lane%32 = j*8 + hd: j = edge slot (0..3), hd = head (0..7, 16 dims each).
// Bulk-convert + depth-1: measured best (round 9 convert-and-consume ✗, round 11 depth-2 ✗).
__global__ __launch_bounds__(256) void edge_attn_kernel(
    const unsigned short* __restrict__ Qb, const unsigned char* __restrict__ KV8,
    const int2* __restrict__ off2, const int* __restrict__ psrc,
    unsigned short* __restrict__ aggb, int n) {
    int node = (blockIdx.x * 256 + threadIdx.x) >> 5;
    int l32 = threadIdx.x & 31;
    if (node >= n) return;          // whole 32-lane group exits together
    int2 se = off2[node];
    int start = se.x, end = se.y;
    int j = l32 >> 3, hd = l32 & 7;

    const unsigned short* qp = &Qb[(size_t)node * D + hd * 16];
    uint4 qa = *(const uint4*)qp;
    uint4 qb = *(const uint4*)(qp + 8);
    float q[16];
    q[0] = bf2f_lo(qa.x);  q[1] = bf2f_hi(qa.x);
    q[2] = bf2f_lo(qa.y);  q[3] = bf2f_hi(qa.y);
    q[4] = bf2f_lo(qa.z);  q[5] = bf2f_hi(qa.z);
    q[6] = bf2f_lo(qa.w);  q[7] = bf2f_hi(qa.w);
    q[8] = bf2f_lo(qb.x);  q[9] = bf2f_hi(qb.x);
    q[10] = bf2f_lo(qb.y); q[11] = bf2f_hi(qb.y);
    q[12] = bf2f_lo(qb.z); q[13] = bf2f_hi(qb.z);
    q[14] = bf2f_lo(qb.w); q[15] = bf2f_hi(qb.w);

    float l = 0.f;
    float acc[16] = {};

    if (start < end) {
        int s0 = psrc[min(start + j, end - 1)];
        int s1 = (start + 4 < end) ? psrc[min(start + 4 + j, end - 1)] : 0;
        const unsigned char* kvp = &KV8[(size_t)s0 * 256 + hd * 16];
        uint4 ku = *(const uint4*)kvp;
        uint4 vu = *(const uint4*)(kvp + 128);
        for (int base = start; base < end; base += 4) {
            // issue next iteration's KV loads first (address ready via s1)
            const unsigned char* kvpn = &KV8[(size_t)s1 * 256 + hd * 16];
            uint4 kun = *(const uint4*)kvpn;
            uint4 vun = *(const uint4*)(kvpn + 128);
            // prefetch psrc two iterations ahead
            int s2 = (base + 8 < end) ? psrc[min(base + 8 + j, end - 1)] : 0;
            bool valid = (base + j) < end;

            float kf[16], vf[16];
            {
                f32x2 t;
                t = __builtin_amdgcn_cvt_pk_f32_fp8(ku.x, false); kf[0] = t.x;  kf[1] = t.y;
                t = __builtin_amdgcn_cvt_pk_f32_fp8(ku.x, true);  kf[2] = t.x;  kf[3] = t.y;
                t = __builtin_amdgcn_cvt_pk_f32_fp8(ku.y, false); kf[4] = t.x;  kf[5] = t.y;
                t = __builtin_amdgcn_cvt_pk_f32_fp8(ku.y, true);  kf[6] = t.x;  kf[7] = t.y;
                t = __builtin_amdgcn_cvt_pk_f32_fp8(ku.z, false); kf[8] = t.x;  kf[9] = t.y;
                t = __builtin_amdgcn_cvt_pk_f32_fp8(ku.z, true);  kf[10] = t.x; kf[11] = t.y;
                t = __builtin_amdgcn_cvt_pk_f32_fp8(ku.w, false); kf[12] = t.x; kf[13] = t.y;
                t = __builtin_amdgcn_cvt_pk_f32_fp8(ku.w, true);  kf[14] = t.x; kf[15] = t.y;
                t = __builtin_amdgcn_cvt_pk_f32_fp8(vu.x, false); vf[0] = t.x;  vf[1] = t.y;
                t = __builtin_amdgcn_cvt_pk_f32_fp8(vu.x, true);  vf[2] = t.x;  vf[3] = t.y;
                t = __builtin_amdgcn_cvt_pk_f32_fp8(vu.y, false); vf[4] = t.x;  vf[5] = t.y;
                t = __builtin_amdgcn_cvt_pk_f32_fp8(vu.y, true);  vf[6] = t.x;  vf[7] = t.y;
                t = __builtin_amdgcn_cvt_pk_f32_fp8(vu.z, false); vf[8] = t.x;  vf[9] = t.y;
                t = __builtin_amdgcn_cvt_pk_f32_fp8(vu.z, true);  vf[10] = t.x; vf[11] = t.y;
                t = __builtin_amdgcn_cvt_pk_f32_fp8(vu.w, false); vf[12] = t.x; vf[13] = t.y;
                t = __builtin_amdgcn_cvt_pk_f32_fp8(vu.w, true);  vf[14] = t.x; vf[15] = t.y;
            }

            float sc = q[0] * kf[0];
#pragma unroll
            for (int i = 1; i < 16; ++i) sc = fmaf(q[i], kf[i], sc);

            float p = valid ? __expf(sc) : 0.f;
            l += p;
#pragma unroll
            for (int i = 0; i < 16; ++i) acc[i] = fmaf(p, vf[i], acc[i]);
            ku = kun; vu = vun; s1 = s2;
        }
    }

    // combine the 4 edge slots (lanes differing in bits 3,4 — stays inside the 32-lane node group)
#pragma unroll
    for (int off = 8; off <= 16; off <<= 1) {
        l += __shfl_xor(l, off, 64);
#pragma unroll
        for (int i = 0; i < 16; ++i) acc[i] += __shfl_xor(acc[i], off, 64);
    }
    float inv = (l > 0.f) ? 1.f / l : 0.f;
    if (j == 0) {
        uint4 o0, o1;
        o0.x = (unsigned int)f2bf(acc[0] * inv) | ((unsigned int)f2bf(acc[1] * inv) << 16);
        o0.y = (unsigned int)f2bf(acc[2] * inv) | ((unsigned int)f2bf(acc[3] * inv) << 16);
        o0.z = (unsigned int)f2bf(acc[4] * inv) | ((unsigned int)f2bf(acc[5] * inv) << 16);
        o0.w = (unsigned int)f2bf(acc[6] * inv) | ((unsigned int)f2bf(acc[7] * inv) << 16);
        o1.x = (unsigned int)f2bf(acc[8] * inv) | ((unsigned int)f2bf(acc[9] * inv) << 16);
        o1.y = (unsigned int)f2bf(acc[10] * inv) | ((unsigned int)f2bf(acc[11] * inv) << 16);
        o1.z = (unsigned int)f2bf(acc[12] * inv) | ((unsigned int)f2bf(acc[13] * inv) << 16);
        o1.w = (unsigned int)f2bf(acc[14] * inv) | ((unsigned int)f2bf(acc[15] * inv) << 16);
        unsigned short* op = &aggb[(size_t)node * D + hd * 16];
        *(uint4*)op = o0;
        *(uint4*)(op + 8) = o1;
    }
}

// ---------------- Output GEMM + bias + residual + LayerNorm (frag-ordered WTo, coalesced) ----------------
__global__ __launch_bounds__(256) void out_ln_mfma_kernel(
    const unsigned short* __restrict__ aggb, const unsigned short* __restrict__ WTo,
    const float* __restrict__ bo, const float* __restrict__ hres,
    const float* __restrict__ gamma, const float* __restrict__ beta,
    float* __restrict__ out, int n) {
    int tid = threadIdx.x;
    int lane = tid & 63, wave = tid >> 6;
    int quad = lane >> 4, l15 = lane & 15;
    int rt = blockIdx.x * 64 + wave * 16;

    int rowA = min(rt + l15, n - 1);
    bf16x8 af[4];
#pragma unroll
    for (int ks = 0; ks < 4; ++ks)
        af[ks] = *(const bf16x8*)&aggb[(size_t)rowA * D + ks * 32 + quad * 8];

    f32x4 acc[8];
#pragma unroll
    for (int ct = 0; ct < 8; ++ct) {
        acc[ct] = (f32x4){0.f, 0.f, 0.f, 0.f};
#pragma unroll
        for (int ks = 0; ks < 4; ++ks) {
            bf16x8 bfr = *(const bf16x8*)&WTo[(size_t)((ct * 4 + ks) * 64 + lane) * 8];
            acc[ct] = __builtin_amdgcn_mfma_f32_16x16x32_bf16(af[ks], bfr, acc[ct], 0, 0, 0);
        }
    }

    float bb[8], gg[8], be[8];
#pragma unroll
    for (int ct = 0; ct < 8; ++ct) {
        int col = ct * 16 + l15;
        bb[ct] = bo[col];
        gg[ct] = gamma[col];
        be[ct] = beta[col];
    }
#pragma unroll
    for (int ct = 0; ct < 8; ++ct) {
        int col = ct * 16 + l15;
#pragma unroll
        for (int r = 0; r < 4; ++r) {
            int row = rt + quad * 4 + r;
            float hv = (row < n) ? hres[(size_t)row * D + col] : 0.f;
            acc[ct][r] = acc[ct][r] + bb[ct] + hv;
        }
    }

#pragma unroll
    for (int r = 0; r < 4; ++r) {
        float s1 = 0.f, s2 = 0.f;
#pragma unroll
        for (int ct = 0; ct < 8; ++ct) {
            float v = acc[ct][r];
            s1 += v;
            s2 += v * v;
        }
        s1 += __shfl_xor(s1, 1, 64); s2 += __shfl_xor(s2, 1, 64);
        s1 += __shfl_xor(s1, 2, 64); s2 += __shfl_xor(s2, 2, 64);
        s1 += __shfl_xor(s1, 4, 64); s2 += __shfl_xor(s2, 4, 64);
        s1 += __shfl_xor(s1, 8, 64); s2 += __shfl_xor(s2, 8, 64);
        float mu = s1 * (1.f / 128.f);
        float var = s2 * (1.f / 128.f) - mu * mu;
        float rs = rsqrtf(fmaxf(var, 0.f) + EPS);
        int row = rt + quad * 4 + r;
        if (row < n) {
#pragma unroll
            for (int ct = 0; ct < 8; ++ct) {
                int col = ct * 16 + l15;
                out[(size_t)row * D + col] = (acc[ct][r] - mu) * rs * gg[ct] + be[ct];
            }
        }
    }
}

// ---------------- launch ----------------
extern "C" void kernel_launch(void* const* d_in, const int* in_sizes, int n_in,
                              void* d_out, int out_size, void* d_ws, size_t ws_size,
                              hipStream_t stream) {
    const float* h     = (const float*)d_in[0];
    const float* Wq    = (const float*)d_in[1];
    const float* bq    = (const float*)d_in[2];
    const float* Wk    = (const float*)d_in[3];
    const float* bk    = (const float*)d_in[4];
    const float* Wv    = (const float*)d_in[5];
    const float* bv    = (const float*)d_in[6];
    const float* Wo    = (const float*)d_in[7];
    const float* bo    = (const float*)d_in[8];
    const float* gamma = (const float*)d_in[9];
    const float* beta  = (const float*)d_in[10];
    const int* src     = (const int*)d_in[11];
    const int* dst     = (const int*)d_in[12];
    float* out = (float*)d_out;

    int N = in_sizes[0] / D;
    int E = in_sizes[11];

    // workspace layout
    unsigned short* Qb = (unsigned short*)d_ws;               // N*D bf16
    unsigned short* Ab = Qb + (size_t)N * D;                  // N*D bf16
    unsigned short* WT = Ab + (size_t)N * D;                  // 4*D*D bf16 (frag order)
    unsigned char* KV8 = (unsigned char*)(WT + 4 * D * D);    // N*256 fp8 (K|V interleaved)
    int* counts   = (int*)(KV8 + (size_t)N * 256);            // N*CPAD (padded, 1/line)
    int* cursor   = counts + (size_t)N * CPAD;                // 16 ints (zeroed with counts)
    int2* off2    = (int2*)(cursor + 16);                     // N {start,end}
    int* ticket   = (int*)(off2 + N);                         // E
    int* psrc     = ticket + E;                               // E

    int nchunks = (N + 255) / 256;
    int e4blocks = ((E + 3) / 4 + 255) / 256;
    int nqkv = (N + 63) / 64;

    hipMemsetAsync(counts, 0, ((size_t)N * CPAD + 16) * sizeof(int), stream);
    prep_kernel<<<64 + e4blocks, 256, 0, stream>>>(Wq, Wk, Wv, Wo, WT, dst, counts, ticket, E);
    alloc_kernel<<<nchunks, 256, 0, stream>>>(counts, cursor, off2, N);
    scatter_qkv_kernel<<<e4blocks + nqkv, 256, 0, stream>>>(
        dst, src, ticket, off2, psrc, E, e4blocks,
        h, WT, bq, bk, bv, Qb, KV8, N);
    edge_attn_kernel<<<(N + 7) / 8, 256, 0, stream>>>(Qb, KV8, off2, psrc, Ab, N);
    out_ln_mfma_kernel<<<(N + 63) / 64, 256, 0, stream>>>(Ab, WT + 3 * D * D, bo, h, gamma, beta, out, N);
}

// Round 13
// 216.088 us; speedup vs baseline: 1.1794x; 1.0107x over previous
//
#include <hip/hip_runtime.h>
#include <hip/hip_bf16.h>
#include <math.h>

#define D 128
#define EPS 1e-12f
#define CPAD 16   // one counter per 64B cache line: kills same-line atomic serialization

typedef __attribute__((ext_vector_type(8))) short bf16x8;
typedef __attribute__((ext_vector_type(4))) float f32x4;
typedef __attribute__((ext_vector_type(2))) float f32x2;

// float -> bf16 round-to-nearest-even (finite inputs)
__device__ __forceinline__ unsigned short f2bf(float f) {
    unsigned int u = __float_as_uint(f);
    return (unsigned short)((u + 0x7fffu + ((u >> 16) & 1u)) >> 16);
}
__device__ __forceinline__ float bf2f_lo(unsigned int packed) {
    return __uint_as_float(packed << 16);
}
__device__ __forceinline__ float bf2f_hi(unsigned int packed) {
    return __uint_as_float(packed & 0xffff0000u);
}
__device__ __forceinline__ unsigned char f2fp8(float f) {
    return (unsigned char)__builtin_amdgcn_cvt_pk_fp8_f32(f, f, 0, false);
}

// ---------------- merged: W convert to MFMA-fragment order (blocks 0..63) + ticket ----------------
// Fragment order: WT[m*16384 + ((ct*4+ks)*64 + quad*16 + l15)*8 + j]
//   holds element (n = ct*16+l15, k = ks*32+quad*8+j) of W_m^T  (bf16)
// Ticket atomics live HERE (overlapped with W-conv, coalesced ticket store) — moving them
// into scatter (round 10) tripled scatter's time via the dependent atomic->store chain.
__global__ __launch_bounds__(256) void prep_kernel(
    const float* __restrict__ Wq, const float* __restrict__ Wk,
    const float* __restrict__ Wv, const float* __restrict__ Wo,
    unsigned short* __restrict__ WT,
    const int* __restrict__ dst, int* __restrict__ counts,
    int* __restrict__ ticket, int E) {
    int bx = blockIdx.x;
    int tid = threadIdx.x;
    if (bx < 64) {
        __shared__ unsigned short tile[32][33];
        int m = bx >> 4;
        int t = bx & 15;
        const float* W = (m == 0) ? Wq : (m == 1) ? Wk : (m == 2) ? Wv : Wo;
        int r0 = (t & 3) * 32;   // k block
        int c0 = (t >> 2) * 32;  // n block
        int row = tid >> 3, c4 = (tid & 7) * 4;
        float4 v = *(const float4*)&W[(size_t)(r0 + row) * D + c0 + c4];
        tile[c4 + 0][row] = f2bf(v.x);
        tile[c4 + 1][row] = f2bf(v.y);
        tile[c4 + 2][row] = f2bf(v.z);
        tile[c4 + 3][row] = f2bf(v.w);
        __syncthreads();
        unsigned int lo = (unsigned int)tile[row][c4] | ((unsigned int)tile[row][c4 + 1] << 16);
        unsigned int hi = (unsigned int)tile[row][c4 + 2] | ((unsigned int)tile[row][c4 + 3] << 16);
        uint2 pk; pk.x = lo; pk.y = hi;
        int n = c0 + row;
        int ct = n >> 4, l15 = n & 15;
        int ks = t & 3;
        int quad = c4 >> 3;
        int j = c4 & 7;
        size_t off = (size_t)m * 16384 + (size_t)(((ct * 4 + ks) * 64) + quad * 16 + l15) * 8 + j;
        *(uint2*)&WT[off] = pk;
    } else {
        int e = ((bx - 64) * 256 + tid) * 4;
        if (e >= E) return;
        if (e + 3 < E) {
            int4 d4 = *(const int4*)&dst[e];
            int4 t4;
            t4.x = atomicAdd(&counts[d4.x * CPAD], 1);
            t4.y = atomicAdd(&counts[d4.y * CPAD], 1);
            t4.z = atomicAdd(&counts[d4.z * CPAD], 1);
            t4.w = atomicAdd(&counts[d4.w * CPAD], 1);
            *(int4*)&ticket[e] = t4;
        } else {
            for (int i = e; i < E; ++i) ticket[i] = atomicAdd(&counts[dst[i] * CPAD], 1);
        }
    }
}

// ---------------- block-local inclusive scan helper ----------------
__device__ __forceinline__ int block_incl_scan256(int v, int tid, int* wsum) {
    int lane = tid & 63;
    int wid = tid >> 6;
#pragma unroll
    for (int off = 1; off < 64; off <<= 1) {
        int t = __shfl_up(v, off, 64);
        if (lane >= off) v += t;
    }
    if (lane == 63) wsum[wid] = v;
    __syncthreads();
#pragma unroll
    for (int w = 0; w < 4; ++w)
        if (w < wid) v += wsum[w];
    return v;
}

// ---------------- merged: segment allocator (blocks < nchunks) + QKV MFMA (rest) ----------------
// Allocator: each block scans its 256 node counts, bumps a global cursor ONCE for its base,
// writes off2[node] = {start, end}. Segment order across blocks arbitrary — consumers only
// use per-node [start,end), so semantics unchanged.
// QKV: K and V stored interleaved: KV8[row*256 + 0..127]=K fp8, [128..255]=V fp8.
// LDS staging kept: measured faster than direct-L2 B-fragment reads (round 6: +3-6 µs without).
__global__ __launch_bounds__(256) void alloc_qkv_kernel(
    const int* __restrict__ counts, int* __restrict__ cursor, int2* __restrict__ off2,
    int nchunks,
    const float* __restrict__ h, const unsigned short* __restrict__ WT,
    const float* __restrict__ bq, const float* __restrict__ bk, const float* __restrict__ bv,
    unsigned short* __restrict__ Qb, unsigned char* __restrict__ KV8, int n) {
    __shared__ __align__(16) unsigned short wt[16384];   // 32 KB, frag-ordered (QKV path)
    int bx = blockIdx.x;
    int tid = threadIdx.x;
    if (bx < nchunks) {
        __shared__ int wsum[4];
        __shared__ int basesh;
        int i = bx * 256 + tid;
        int c = (i < n) ? counts[i * CPAD] : 0;
        int incl = block_incl_scan256(c, tid, wsum);
        if (tid == 255) basesh = atomicAdd(cursor, incl);
        __syncthreads();
        int start = basesh + incl - c;
        if (i < n) off2[i] = make_int2(start, start + c);
        return;
    }
    int bid = bx - nchunks;
    int lane = tid & 63, wave = tid >> 6;
    int quad = lane >> 4, l15 = lane & 15;
    int rt = bid * 64 + wave * 16;

    // A-fragments: h rows rt+l15 (clamped; OOB rows never stored), fp32 -> bf16
    int rowA = min(rt + l15, n - 1);
    bf16x8 af[4];
#pragma unroll
    for (int ks = 0; ks < 4; ++ks) {
        const float* ap = &h[(size_t)rowA * D + ks * 32 + quad * 8];
        float4 a0 = *(const float4*)ap;
        float4 a1 = *(const float4*)(ap + 4);
        union { unsigned short u[8]; bf16x8 v; } pk;
        pk.u[0] = f2bf(a0.x); pk.u[1] = f2bf(a0.y);
        pk.u[2] = f2bf(a0.z); pk.u[3] = f2bf(a0.w);
        pk.u[4] = f2bf(a1.x); pk.u[5] = f2bf(a1.y);
        pk.u[6] = f2bf(a1.z); pk.u[7] = f2bf(a1.w);
        af[ks] = pk.v;
    }

    for (int m = 0; m < 3; ++m) {
        // linear 32 KB copy: lane-consecutive uint4, conflict-free both sides
#pragma unroll
        for (int it = 0; it < 8; ++it) {
            int idx = it * 256 + tid;
            *(uint4*)&wt[idx * 8] = *(const uint4*)&WT[(size_t)m * 16384 + idx * 8];
        }
        __syncthreads();

        f32x4 acc[8];
#pragma unroll
        for (int ct = 0; ct < 8; ++ct) {
            acc[ct] = (f32x4){0.f, 0.f, 0.f, 0.f};
#pragma unroll
            for (int ks = 0; ks < 4; ++ks) {
                bf16x8 bfr = *(const bf16x8*)&wt[((ct * 4 + ks) * 64 + lane) * 8];
                acc[ct] = __builtin_amdgcn_mfma_f32_16x16x32_bf16(af[ks], bfr, acc[ct], 0, 0, 0);
            }
        }
        __syncthreads();   // wt consumed before next m overwrites

        const float* bias = (m == 0) ? bq : (m == 1) ? bk : bv;
#pragma unroll
        for (int ct = 0; ct < 8; ++ct) {
            int col = ct * 16 + l15;
            float bb = bias[col];
#pragma unroll
            for (int r = 0; r < 4; ++r) {
                int row = rt + quad * 4 + r;
                if (row < n) {
                    float v = acc[ct][r] + bb;
                    if (m == 0)      Qb[(size_t)row * D + col] = f2bf(v);
                    else if (m == 1) KV8[(size_t)row * 256 + col] = f2fp8(v);
                    else             KV8[(size_t)row * 256 + 128 + col] = f2fp8(v);
                }
            }
        }
    }
}

// ---------------- scatter: psrc fill using allocator bases + prep tickets ----------------
__global__ __launch_bounds__(256) void scatter_kernel(
    const int* __restrict__ dst, const int* __restrict__ src,
    const int* __restrict__ ticket, const int2* __restrict__ off2,
    int* __restrict__ psrc, int E) {
    int e = (blockIdx.x * 256 + threadIdx.x) * 4;
    if (e >= E) return;
    if (e + 3 < E) {
        int4 d4 = *(const int4*)&dst[e];
        int4 s4 = *(const int4*)&src[e];
        int4 t4 = *(const int4*)&ticket[e];
        psrc[off2[d4.x].x + t4.x] = s4.x;
        psrc[off2[d4.y].x + t4.y] = s4.y;
        psrc[off2[d4.z].x + t4.z] = s4.z;
        psrc[off2[d4.w].x + t4.w] = s4.w;
    } else {
        for (int i = e; i < E; ++i) psrc[off2[dst[i]].x + ticket[i]] = src[i];
    }
}

// ---------------- Edge attention (fp8 K/V, interleaved, depth-1 pipelined gather) ----------------
// TWO dst nodes per wave: each 32-lane half owns one node.
// lane%32 = j*8 + hd: j = edge slot (0..3), hd = head (0..7, 16 dims each).
// Bulk-convert + depth-1: measured best (round 9 convert-and-consume ✗, round 11 depth-2 ✗).
__global__ __launch_bounds__(256) void edge_attn_kernel(
    const unsigned short* __restrict__ Qb, const unsigned char* __restrict__ KV8,
    const int2* __restrict__ off2, const int* __restrict__ psrc,
    unsigned short* __restrict__ aggb, int n) {
    int node = (blockIdx.x * 256 + threadIdx.x) >> 5;
    int l32 = threadIdx.x & 31;
    if (node >= n) return;          // whole 32-lane group exits together
    int2 se = off2[node];
    int start = se.x, end = se.y;
    int j = l32 >> 3, hd = l32 & 7;

    const unsigned short* qp = &Qb[(size_t)node * D + hd * 16];
    uint4 qa = *(const uint4*)qp;
    uint4 qb = *(const uint4*)(qp + 8);
    float q[16];
    q[0] = bf2f_lo(qa.x);  q[1] = bf2f_hi(qa.x);
    q[2] = bf2f_lo(qa.y);  q[3] = bf2f_hi(qa.y);
    q[4] = bf2f_lo(qa.z);  q[5] = bf2f_hi(qa.z);
    q[6] = bf2f_lo(qa.w);  q[7] = bf2f_hi(qa.w);
    q[8] = bf2f_lo(qb.x);  q[9] = bf2f_hi(qb.x);
    q[10] = bf2f_lo(qb.y); q[11] = bf2f_hi(qb.y);
    q[12] = bf2f_lo(qb.z); q[13] = bf2f_hi(qb.z);
    q[14] = bf2f_lo(qb.w); q[15] = bf2f_hi(qb.w);

    float l = 0.f;
    float acc[16] = {};

    if (start < end) {
        int s0 = psrc[min(start + j, end - 1)];
        int s1 = (start + 4 < end) ? psrc[min(start + 4 + j, end - 1)] : 0;
        const unsigned char* kvp = &KV8[(size_t)s0 * 256 + hd * 16];
        uint4 ku = *(const uint4*)kvp;
        uint4 vu = *(const uint4*)(kvp + 128);
        for (int base = start; base < end; base += 4) {
            // issue next iteration's KV loads first (address ready via s1)
            const unsigned char* kvpn = &KV8[(size_t)s1 * 256 + hd * 16];
            uint4 kun = *(const uint4*)kvpn;
            uint4 vun = *(const uint4*)(kvpn + 128);
            // prefetch psrc two iterations ahead
            int s2 = (base + 8 < end) ? psrc[min(base + 8 + j, end - 1)] : 0;
            bool valid = (base + j) < end;

            float kf[16], vf[16];
            {
                f32x2 t;
                t = __builtin_amdgcn_cvt_pk_f32_fp8(ku.x, false); kf[0] = t.x;  kf[1] = t.y;
                t = __builtin_amdgcn_cvt_pk_f32_fp8(ku.x, true);  kf[2] = t.x;  kf[3] = t.y;
                t = __builtin_amdgcn_cvt_pk_f32_fp8(ku.y, false); kf[4] = t.x;  kf[5] = t.y;
                t = __builtin_amdgcn_cvt_pk_f32_fp8(ku.y, true);  kf[6] = t.x;  kf[7] = t.y;
                t = __builtin_amdgcn_cvt_pk_f32_fp8(ku.z, false); kf[8] = t.x;  kf[9] = t.y;
                t = __builtin_amdgcn_cvt_pk_f32_fp8(ku.z, true);  kf[10] = t.x; kf[11] = t.y;
                t = __builtin_amdgcn_cvt_pk_f32_fp8(ku.w, false); kf[12] = t.x; kf[13] = t.y;
                t = __builtin_amdgcn_cvt_pk_f32_fp8(ku.w, true);  kf[14] = t.x; kf[15] = t.y;
                t = __builtin_amdgcn_cvt_pk_f32_fp8(vu.x, false); vf[0] = t.x;  vf[1] = t.y;
                t = __builtin_amdgcn_cvt_pk_f32_fp8(vu.x, true);  vf[2] = t.x;  vf[3] = t.y;
                t = __builtin_amdgcn_cvt_pk_f32_fp8(vu.y, false); vf[4] = t.x;  vf[5] = t.y;
                t = __builtin_amdgcn_cvt_pk_f32_fp8(vu.y, true);  vf[6] = t.x;  vf[7] = t.y;
                t = __builtin_amdgcn_cvt_pk_f32_fp8(vu.z, false); vf[8] = t.x;  vf[9] = t.y;
                t = __builtin_amdgcn_cvt_pk_f32_fp8(vu.z, true);  vf[10] = t.x; vf[11] = t.y;
                t = __builtin_amdgcn_cvt_pk_f32_fp8(vu.w, false); vf[12] = t.x; vf[13] = t.y;
                t = __builtin_amdgcn_cvt_pk_f32_fp8(vu.w, true);  vf[14] = t.x; vf[15] = t.y;
            }

            float sc = q[0] * kf[0];
#pragma unroll
            for (int i = 1; i < 16; ++i) sc = fmaf(q[i], kf[i], sc);

            float p = valid ? __expf(sc) : 0.f;
            l += p;
#pragma unroll
            for (int i = 0; i < 16; ++i) acc[i] = fmaf(p, vf[i], acc[i]);
            ku = kun; vu = vun; s1 = s2;
        }
    }

    // combine the 4 edge slots (lanes differing in bits 3,4 — stays inside the 32-lane node group)
#pragma unroll
    for (int off = 8; off <= 16; off <<= 1) {
        l += __shfl_xor(l, off, 64);
#pragma unroll
        for (int i = 0; i < 16; ++i) acc[i] += __shfl_xor(acc[i], off, 64);
    }
    float inv = (l > 0.f) ? 1.f / l : 0.f;
    if (j == 0) {
        uint4 o0, o1;
        o0.x = (unsigned int)f2bf(acc[0] * inv) | ((unsigned int)f2bf(acc[1] * inv) << 16);
        o0.y = (unsigned int)f2bf(acc[2] * inv) | ((unsigned int)f2bf(acc[3] * inv) << 16);
        o0.z = (unsigned int)f2bf(acc[4] * inv) | ((unsigned int)f2bf(acc[5] * inv) << 16);
        o0.w = (unsigned int)f2bf(acc[6] * inv) | ((unsigned int)f2bf(acc[7] * inv) << 16);
        o1.x = (unsigned int)f2bf(acc[8] * inv) | ((unsigned int)f2bf(acc[9] * inv) << 16);
        o1.y = (unsigned int)f2bf(acc[10] * inv) | ((unsigned int)f2bf(acc[11] * inv) << 16);
        o1.z = (unsigned int)f2bf(acc[12] * inv) | ((unsigned int)f2bf(acc[13] * inv) << 16);
        o1.w = (unsigned int)f2bf(acc[14] * inv) | ((unsigned int)f2bf(acc[15] * inv) << 16);
        unsigned short* op = &aggb[(size_t)node * D + hd * 16];
        *(uint4*)op = o0;
        *(uint4*)(op + 8) = o1;
    }
}

// ---------------- Output GEMM + bias + residual + LayerNorm (frag-ordered WTo, coalesced) ----------------
__global__ __launch_bounds__(256) void out_ln_mfma_kernel(
    const unsigned short* __restrict__ aggb, const unsigned short* __restrict__ WTo,
    const float* __restrict__ bo, const float* __restrict__ hres,
    const float* __restrict__ gamma, const float* __restrict__ beta,
    float* __restrict__ out, int n) {
    int tid = threadIdx.x;
    int lane = tid & 63, wave = tid >> 6;
    int quad = lane >> 4, l15 = lane & 15;
    int rt = blockIdx.x * 64 + wave * 16;

    int rowA = min(rt + l15, n - 1);
    bf16x8 af[4];
#pragma unroll
    for (int ks = 0; ks < 4; ++ks)
        af[ks] = *(const bf16x8*)&aggb[(size_t)rowA * D + ks * 32 + quad * 8];

    f32x4 acc[8];
#pragma unroll
    for (int ct = 0; ct < 8; ++ct) {
        acc[ct] = (f32x4){0.f, 0.f, 0.f, 0.f};
#pragma unroll
        for (int ks = 0; ks < 4; ++ks) {
            bf16x8 bfr = *(const bf16x8*)&WTo[(size_t)((ct * 4 + ks) * 64 + lane) * 8];
            acc[ct] = __builtin_amdgcn_mfma_f32_16x16x32_bf16(af[ks], bfr, acc[ct], 0, 0, 0);
        }
    }

    float bb[8], gg[8], be[8];
#pragma unroll
    for (int ct = 0; ct < 8; ++ct) {
        int col = ct * 16 + l15;
        bb[ct] = bo[col];
        gg[ct] = gamma[col];
        be[ct] = beta[col];
    }
#pragma unroll
    for (int ct = 0; ct < 8; ++ct) {
        int col = ct * 16 + l15;
#pragma unroll
        for (int r = 0; r < 4; ++r) {
            int row = rt + quad * 4 + r;
            float hv = (row < n) ? hres[(size_t)row * D + col] : 0.f;
            acc[ct][r] = acc[ct][r] + bb[ct] + hv;
        }
    }

#pragma unroll
    for (int r = 0; r < 4; ++r) {
        float s1 = 0.f, s2 = 0.f;
#pragma unroll
        for (int ct = 0; ct < 8; ++ct) {
            float v = acc[ct][r];
            s1 += v;
            s2 += v * v;
        }
        s1 += __shfl_xor(s1, 1, 64); s2 += __shfl_xor(s2, 1, 64);
        s1 += __shfl_xor(s1, 2, 64); s2 += __shfl_xor(s2, 2, 64);
        s1 += __shfl_xor(s1, 4, 64); s2 += __shfl_xor(s2, 4, 64);
        s1 += __shfl_xor(s1, 8, 64); s2 += __shfl_xor(s2, 8, 64);
        float mu = s1 * (1.f / 128.f);
        float var = s2 * (1.f / 128.f) - mu * mu;
        float rs = rsqrtf(fmaxf(var, 0.f) + EPS);
        int row = rt + quad * 4 + r;
        if (row < n) {
#pragma unroll
            for (int ct = 0; ct < 8; ++ct) {
                int col = ct * 16 + l15;
                out[(size_t)row * D + col] = (acc[ct][r] - mu) * rs * gg[ct] + be[ct];
            }
        }
    }
}

// ---------------- launch ----------------
extern "C" void kernel_launch(void* const* d_in, const int* in_sizes, int n_in,
                              void* d_out, int out_size, void* d_ws, size_t ws_size,
                              hipStream_t stream) {
    const float* h     = (const float*)d_in[0];
    const float* Wq    = (const float*)d_in[1];
    const float* bq    = (const float*)d_in[2];
    const float* Wk    = (const float*)d_in[3];
    const float* bk    = (const float*)d_in[4];
    const float* Wv    = (const float*)d_in[5];
    const float* bv    = (const float*)d_in[6];
    const float* Wo    = (const float*)d_in[7];
    const float* bo    = (const float*)d_in[8];
    const float* gamma = (const float*)d_in[9];
    const float* beta  = (const float*)d_in[10];
    const int* src     = (const int*)d_in[11];
    const int* dst     = (const int*)d_in[12];
    float* out = (float*)d_out;

    int N = in_sizes[0] / D;
    int E = in_sizes[11];

    // workspace layout
    unsigned short* Qb = (unsigned short*)d_ws;               // N*D bf16
    unsigned short* Ab = Qb + (size_t)N * D;                  // N*D bf16
    unsigned short* WT = Ab + (size_t)N * D;                  // 4*D*D bf16 (frag order)
    unsigned char* KV8 = (unsigned char*)(WT + 4 * D * D);    // N*256 fp8 (K|V interleaved)
    int* counts   = (int*)(KV8 + (size_t)N * 256);            // N*CPAD (padded, 1/line)
    int* cursor   = counts + (size_t)N * CPAD;                // 16 ints (zeroed with counts)
    int2* off2    = (int2*)(cursor + 16);                     // N {start,end}
    int* ticket   = (int*)(off2 + N);                         // E
    int* psrc     = ticket + E;                               // E

    int nchunks = (N + 255) / 256;
    int e4blocks = ((E + 3) / 4 + 255) / 256;
    int nqkv = (N + 63) / 64;

    hipMemsetAsync(counts, 0, ((size_t)N * CPAD + 16) * sizeof(int), stream);
    prep_kernel<<<64 + e4blocks, 256, 0, stream>>>(Wq, Wk, Wv, Wo, WT, dst, counts, ticket, E);
    alloc_qkv_kernel<<<nchunks + nqkv, 256, 0, stream>>>(
        counts, cursor, off2, nchunks, h, WT, bq, bk, bv, Qb, KV8, N);
    scatter_kernel<<<e4blocks, 256, 0, stream>>>(dst, src, ticket, off2, psrc, E);
    edge_attn_kernel<<<(N + 7) / 8, 256, 0, stream>>>(Qb, KV8, off2, psrc, Ab, N);
    out_ln_mfma_kernel<<<(N + 63) / 64, 256, 0, stream>>>(Ab, WT + 3 * D * D, bo, h, gamma, beta, out, N);
}